// Round 1
// 2170.776 us; speedup vs baseline: 1.0107x; 1.0107x over previous
//
#include <hip/hip_runtime.h>
#include <hip/hip_fp16.h>

namespace {
constexpr int kN = 512;
constexpr int kB = 256;
constexpr int kPowerIters = 30;
constexpr int kFistaIters = 300;
}

typedef __attribute__((ext_vector_type(8))) short bf16x8;
typedef __attribute__((ext_vector_type(4))) float f32x4;

// Device-global scratch (BSS): ignore d_ws entirely. All fully rewritten each call.
__device__ ushort g_Ct[(size_t)kB * kN * kN];          // bf16 C^T, 128 MiB
__device__ __half g_Q16[(size_t)kB * kN * kN];         // fp16 Q (gamma^2-scaled), 128 MiB
__device__ unsigned int g_Q8[(size_t)kB * kN * kN / 4];// fp8 e4m3 of Q/gamma^2, 64 MiB

// ---------------- transpose: C[b][k][i] fp32 -> Ct[b][i][k] bf16 ----------------

__device__ __forceinline__ ushort f32_to_bf16(float f) {
  unsigned int u = __float_as_uint(f);
  unsigned int r = u + 0x7FFFu + ((u >> 16) & 1u);   // RNE
  return (ushort)(r >> 16);
}

__global__ __launch_bounds__(256) void transpose_kernel(const float* __restrict__ C) {
  __shared__ ushort Ts[64][68];
  const int b = blockIdx.y;
  const int tk = blockIdx.x >> 3, ti = blockIdx.x & 7;
  const int k0 = tk * 64, i0 = ti * 64;
  const float* Cb = C + (size_t)b * kN * kN;
  ushort* Ct = g_Ct + (size_t)b * kN * kN;
  const int t = threadIdx.x;
  const int cq = t & 15;
  const int r0 = t >> 4;  // 0..15
#pragma unroll
  for (int p = 0; p < 4; ++p) {
    const int r = r0 + 16 * p;
    const float4 v = *(const float4*)(Cb + (size_t)(k0 + r) * kN + i0 + 4 * cq);
    ushort4 h;
    h.x = f32_to_bf16(v.x); h.y = f32_to_bf16(v.y);
    h.z = f32_to_bf16(v.z); h.w = f32_to_bf16(v.w);
    *(ushort4*)(&Ts[r][4 * cq]) = h;
  }
  __syncthreads();
#pragma unroll
  for (int p = 0; p < 4; ++p) {
    const int r = r0 + 16 * p;
    ushort4 h;
    h.x = Ts[4 * cq + 0][r];
    h.y = Ts[4 * cq + 1][r];
    h.z = Ts[4 * cq + 2][r];
    h.w = Ts[4 * cq + 3][r];
    *(ushort4*)(Ct + (size_t)(i0 + r) * kN + k0 + 4 * cq) = h;
  }
}

// ---------------- build: Q16 = gamma^2 * Ct * Ct^T via bf16 MFMA ----------------
// 128x128 tile/block, 4 waves in 2x2 quadrants, 4x4 16x16 MFMA tiles per wave.
// Fused epilogue also emits fp8(raw acc) for the power phase (q8_kernel removed):
// Q symmetric and mirror tiles accumulate bitwise-identical sums, so each lane packs
// its 4 row-consecutive values into one dword and stores them transposed.

__global__ __launch_bounds__(256) void build_q_kernel(const float* __restrict__ gamma) {
  __shared__ ushort As[128][40];   // [i_local][k_local], pitch 40 halves (16B-aligned rows)
  __shared__ ushort Bs[128][40];
  const int b = blockIdx.y;
  const int ti = blockIdx.x >> 2, tj = blockIdx.x & 3;
  const int i0 = ti * 128, j0 = tj * 128;
  const ushort* Ct = g_Ct + (size_t)b * kN * kN;
  const float gg = gamma[b];
  const float g2 = gg * gg;
  const int t = threadIdx.x;
  const int lane = t & 63, w = t >> 6;
  const int wr = w >> 1, wc = w & 1;
  const int m = lane & 15, q = lane >> 4;
  const int sr = t >> 2;   // 0..63 staging row
  const int ss = t & 3;    // 0..3 staging 8-half segment

  f32x4 acc[4][4];
#pragma unroll
  for (int g = 0; g < 4; ++g)
#pragma unroll
    for (int h = 0; h < 4; ++h) acc[g][h] = (f32x4){0.f, 0.f, 0.f, 0.f};

  for (int k0 = 0; k0 < kN; k0 += 32) {
    const int4 a0 = *(const int4*)(Ct + (size_t)(i0 + sr) * kN + k0 + 8 * ss);
    const int4 a1 = *(const int4*)(Ct + (size_t)(i0 + sr + 64) * kN + k0 + 8 * ss);
    const int4 b0 = *(const int4*)(Ct + (size_t)(j0 + sr) * kN + k0 + 8 * ss);
    const int4 b1 = *(const int4*)(Ct + (size_t)(j0 + sr + 64) * kN + k0 + 8 * ss);
    __syncthreads();
    *(int4*)(&As[sr][8 * ss]) = a0;
    *(int4*)(&As[sr + 64][8 * ss]) = a1;
    *(int4*)(&Bs[sr][8 * ss]) = b0;
    *(int4*)(&Bs[sr + 64][8 * ss]) = b1;
    __syncthreads();
    bf16x8 fa[4], fb[4];
#pragma unroll
    for (int g = 0; g < 4; ++g)
      fa[g] = *(const bf16x8*)(&As[64 * wr + 16 * g + m][8 * q]);
#pragma unroll
    for (int h = 0; h < 4; ++h)
      fb[h] = *(const bf16x8*)(&Bs[64 * wc + 16 * h + m][8 * q]);
#pragma unroll
    for (int g = 0; g < 4; ++g)
#pragma unroll
      for (int h = 0; h < 4; ++h)
        acc[g][h] = __builtin_amdgcn_mfma_f32_16x16x32_bf16(fa[g], fb[h], acc[g][h], 0, 0, 0);
  }

  __half* Qb = g_Q16 + (size_t)b * kN * kN;
  unsigned char* q8b = (unsigned char*)g_Q8 + (size_t)b * kN * kN;
#pragma unroll
  for (int g = 0; g < 4; ++g) {
#pragma unroll
    for (int h = 0; h < 4; ++h) {
      const int col = j0 + 64 * wc + 16 * h + m;
      const int rbase = i0 + 64 * wr + 16 * g + 4 * q;
#pragma unroll
      for (int r = 0; r < 4; ++r)
        Qb[(size_t)(rbase + r) * kN + col] = __float2half(acc[g][h][r] * g2);
      // fp8 of raw (un-scaled) acc, stored transposed: Q8[col][rbase..rbase+3]
      unsigned int pk = 0;
      pk = __builtin_amdgcn_cvt_pk_fp8_f32(acc[g][h][0], acc[g][h][1], pk, false);
      pk = __builtin_amdgcn_cvt_pk_fp8_f32(acc[g][h][2], acc[g][h][3], pk, true);
      *(unsigned int*)(q8b + (size_t)col * kN + rbase) = pk;
    }
  }
}

// ---------------- solver helpers ----------------

__device__ __forceinline__ void fma8(const int4 raw, const float yj, float* acc) {
  const __half2* h2 = reinterpret_cast<const __half2*>(&raw);
#pragma unroll
  for (int k = 0; k < 4; ++k) {
    const float2 f = __half22float2(h2[k]);
    acc[2 * k]     = fmaf(f.x, yj, acc[2 * k]);
    acc[2 * k + 1] = fmaf(f.y, yj, acc[2 * k + 1]);
  }
}

// ---------------- fused per-batch solver: 16 waves, two-stage reductions ----------------

__global__ __launch_bounds__(1024) void solver_kernel(const float* __restrict__ rets,
                                                      float* __restrict__ out) {
  __shared__ float yv_s[kN];
  __shared__ short yi_s[kN];
  __shared__ float partial[16 * kN];  // 32 KiB
  __shared__ float zred_s[kN];
  __shared__ float red_s[8];
  __shared__ int nact_s;
  __shared__ int done_s;

  const int t = threadIdx.x;          // 0..1023
  const int lane = t & 63;
  const int w = t >> 6;               // 0..15
  const int b = blockIdx.x;
  const int4* Q16v = (const int4*)(g_Q16 + (size_t)b * kN * kN);
  const uint2* Q8v = (const uint2*)g_Q8 + (size_t)b * (kN * kN / 8);

  // ---- power iteration on fp8 Q (30 iters), normalization folded into matvec ----
  if (t < kN) yv_s[t] = 0.044194173824159216f;  // 1/sqrt(512), already unit norm
  if (t == 0) done_s = 0;
  __syncthreads();

  float invn = 1.0f;
  for (int it = 0; it < kPowerIters; ++it) {
    float acc[8] = {0.f, 0.f, 0.f, 0.f, 0.f, 0.f, 0.f, 0.f};
#pragma unroll 8
    for (int k = w; k < kN; k += 16) {
      const uint2 raw = Q8v[(size_t)k * 64 + lane];
      const float yj = yv_s[k];
      acc[0] = fmaf(__builtin_amdgcn_cvt_f32_fp8(raw.x, 0), yj, acc[0]);
      acc[1] = fmaf(__builtin_amdgcn_cvt_f32_fp8(raw.x, 1), yj, acc[1]);
      acc[2] = fmaf(__builtin_amdgcn_cvt_f32_fp8(raw.x, 2), yj, acc[2]);
      acc[3] = fmaf(__builtin_amdgcn_cvt_f32_fp8(raw.x, 3), yj, acc[3]);
      acc[4] = fmaf(__builtin_amdgcn_cvt_f32_fp8(raw.y, 0), yj, acc[4]);
      acc[5] = fmaf(__builtin_amdgcn_cvt_f32_fp8(raw.y, 1), yj, acc[5]);
      acc[6] = fmaf(__builtin_amdgcn_cvt_f32_fp8(raw.y, 2), yj, acc[6]);
      acc[7] = fmaf(__builtin_amdgcn_cvt_f32_fp8(raw.y, 3), yj, acc[7]);
    }
    float4* pp = (float4*)&partial[(w << 9) + (lane << 3)];
    pp[0] = make_float4(acc[0] * invn, acc[1] * invn, acc[2] * invn, acc[3] * invn);
    pp[1] = make_float4(acc[4] * invn, acc[5] * invn, acc[6] * invn, acc[7] * invn);
    __syncthreads();
    if (t < kN) {
      float u = 0.f;
#pragma unroll
      for (int ww = 0; ww < 16; ++ww) u += partial[(ww << 9) + t];
      yv_s[t] = u;                    // unnormalized; next matvec scales by invn
      float qq = u * u;
#pragma unroll
      for (int m2 = 32; m2 > 0; m2 >>= 1) qq += __shfl_xor(qq, m2, 64);
      if (lane == 0) red_s[w] = qq;
    }
    __syncthreads();
    float n2 = 0.f;
#pragma unroll
    for (int i = 0; i < 8; ++i) n2 += red_s[i];
    invn = 1.0f / (sqrtf(n2) + 1e-12f);
    // red_s is re-written only after the NEXT iteration's barrier -> no extra barrier needed
  }

  // ---- Rayleigh on fp16 Q: lam = v^T Q v (2nd-order robust to v error) ----
  float eta;
  {
    float acc[8] = {0.f, 0.f, 0.f, 0.f, 0.f, 0.f, 0.f, 0.f};
#pragma unroll 8
    for (int k = w; k < kN; k += 16) {
      const int4 raw = Q16v[(size_t)k * 64 + lane];
      fma8(raw, yv_s[k], acc);
    }
    float4* pp = (float4*)&partial[(w << 9) + (lane << 3)];
    pp[0] = make_float4(acc[0] * invn, acc[1] * invn, acc[2] * invn, acc[3] * invn);
    pp[1] = make_float4(acc[4] * invn, acc[5] * invn, acc[6] * invn, acc[7] * invn);
    __syncthreads();
    if (t < kN) {
      float u = 0.f;
#pragma unroll
      for (int ww = 0; ww < 16; ++ww) u += partial[(ww << 9) + t];
      const float vt = yv_s[t] * invn;
      float ql = vt * u;
#pragma unroll
      for (int m2 = 32; m2 > 0; m2 >>= 1) ql += __shfl_xor(ql, m2, 64);
      if (lane == 0) red_s[w] = ql;
    }
    __syncthreads();
    float lam = 0.f;
#pragma unroll
    for (int i = 0; i < 8; ++i) lam += red_s[i];
    eta = 1.0f / (2.0f * 1.06f * lam + 1e-8f);  // 1.06 safety: fp8 direction noise
  }

  // ---- FISTA: wave0 owns all scalar state; early-exit at numerical fixed point ----
  float w8[8], y8[8], r8[8];
  float tf = 1.0f;
  if (t < kN) { yv_s[t] = 1.0f / 512.0f; yi_s[t] = (short)t; }
  if (t == 0) nact_s = kN;
  if (w == 0) {
#pragma unroll
    for (int c = 0; c < 8; ++c) {
      w8[c] = 1.0f / 512.0f;
      y8[c] = 1.0f / 512.0f;
      r8[c] = rets[b * kN + 64 * c + lane];
    }
  }
  __syncthreads();

  for (int it = 0; it < kFistaIters; ++it) {
    const int na = nact_s;
    // sparse matvec: rows strided over 16 waves
    float acc[8] = {0.f, 0.f, 0.f, 0.f, 0.f, 0.f, 0.f, 0.f};
#pragma unroll 4
    for (int k = w; k < na; k += 16) {
      const int row = yi_s[k];
      const int4 raw = Q16v[(size_t)row * 64 + lane];
      fma8(raw, yv_s[k], acc);
    }
    float4* pp = (float4*)&partial[(w << 9) + (lane << 3)];
    pp[0] = make_float4(acc[0], acc[1], acc[2], acc[3]);
    pp[1] = make_float4(acc[4], acc[5], acc[6], acc[7]);
    __syncthreads();
    // stage A: parallel reduce of 16 partials per component
    if (t < kN) {
      float u = 0.f;
#pragma unroll
      for (int ww = 0; ww < 16; ++ww) u += partial[(ww << 9) + t];
      zred_s[t] = u;
    }
    __syncthreads();

    if (w == 0) {
      float z8[8];
#pragma unroll
      for (int c = 0; c < 8; ++c) {
        const float u = zred_s[(c << 6) + lane];
        z8[c] = y8[c] - eta * (2.0f * u - r8[c]);
      }
      // Michelot projection threshold (shuffle-only)
      float s = 0.f;
#pragma unroll
      for (int c = 0; c < 8; ++c) s += z8[c];
#pragma unroll
      for (int m2 = 32; m2 > 0; m2 >>= 1) s += __shfl_xor(s, m2, 64);
      float theta = (s - 1.0f) * (1.0f / 512.0f);
      int prev = kN;
      for (int r = 0; r < 60; ++r) {
        float ss = 0.f, cc = 0.f;
#pragma unroll
        for (int c = 0; c < 8; ++c)
          if (z8[c] > theta) { ss += z8[c]; cc += 1.0f; }
#pragma unroll
        for (int m2 = 32; m2 > 0; m2 >>= 1) {
          ss += __shfl_xor(ss, m2, 64);
          cc += __shfl_xor(cc, m2, 64);
        }
        const int cnt = (int)(cc + 0.5f);
        if (cnt == prev) break;
        theta = (ss - 1.0f) / cc;
        prev = cnt;
      }
      // update + deterministic compaction (i-ascending: c-major, lane-minor)
      const float t_new = 0.5f * (1.0f + sqrtf(1.0f + 4.0f * tf * tf));
      const float coef = (tf - 1.0f) / t_new;
      tf = t_new;
      int base = 0;
      const unsigned long long lt = (1ull << lane) - 1ull;
      float dmax = 0.f;
#pragma unroll
      for (int c = 0; c < 8; ++c) {
        const float wn = fmaxf(z8[c] - theta, 0.0f);
        const float yn = wn + coef * (wn - w8[c]);
        dmax = fmaxf(dmax, fmaxf(fabsf(wn - w8[c]), fabsf(yn - y8[c])));
        w8[c] = wn;
        y8[c] = yn;
        const bool nz = (yn != 0.0f);
        const unsigned long long mask = __ballot(nz);
        if (nz) {
          const int pos = base + __popcll(mask & lt);
          yi_s[pos] = (short)(64 * c + lane);
          yv_s[pos] = yn;
        }
        base += __popcll(mask);
      }
#pragma unroll
      for (int m2 = 32; m2 > 0; m2 >>= 1) dmax = fmaxf(dmax, __shfl_xor(dmax, m2, 64));
      if (lane == 0) {
        nact_s = base;
        if (dmax < 1e-7f) done_s = 1;  // numerical fixed point: rest of iters are no-ops
      }
    }
    __syncthreads();
    if (done_s) break;
  }

  if (w == 0) {
#pragma unroll
    for (int c = 0; c < 8; ++c) out[b * kN + 64 * c + lane] = w8[c];
  }
}

extern "C" void kernel_launch(void* const* d_in, const int* in_sizes, int n_in,
                              void* d_out, int out_size, void* d_ws, size_t ws_size,
                              hipStream_t stream) {
  (void)in_sizes; (void)n_in; (void)out_size; (void)d_ws; (void)ws_size;
  const float* rets  = (const float*)d_in[0];
  const float* cov   = (const float*)d_in[1];
  const float* gamma = (const float*)d_in[2];
  float* out = (float*)d_out;

  transpose_kernel<<<dim3(64, kB), 256, 0, stream>>>(cov);
  build_q_kernel<<<dim3(16, kB), 256, 0, stream>>>(gamma);
  solver_kernel<<<kB, 1024, 0, stream>>>(rets, out);
}

// Round 2
// 2123.383 us; speedup vs baseline: 1.0333x; 1.0223x over previous
//
#include <hip/hip_runtime.h>
#include <hip/hip_fp16.h>

namespace {
constexpr int kN = 512;
constexpr int kB = 256;
constexpr int kPowerIters = 30;
constexpr int kFistaIters = 300;
constexpr int kCacheRows = 120;   // 120 KB LDS row cache (fp16 rows of Q)
}

typedef __attribute__((ext_vector_type(8))) short bf16x8;
typedef __attribute__((ext_vector_type(4))) float f32x4;

// Device-global scratch (BSS): ignore d_ws entirely. All fully rewritten each call.
__device__ ushort g_Ct[(size_t)kB * kN * kN];          // bf16 C^T, 128 MiB
__device__ __half g_Q16[(size_t)kB * kN * kN];         // fp16 Q (gamma^2-scaled), 128 MiB
__device__ unsigned int g_Q8[(size_t)kB * kN * kN / 4];// fp8 e4m3 of Q/gamma^2, 64 MiB

// ---------------- transpose: C[b][k][i] fp32 -> Ct[b][i][k] bf16 ----------------

__device__ __forceinline__ ushort f32_to_bf16(float f) {
  unsigned int u = __float_as_uint(f);
  unsigned int r = u + 0x7FFFu + ((u >> 16) & 1u);   // RNE
  return (ushort)(r >> 16);
}

__global__ __launch_bounds__(256) void transpose_kernel(const float* __restrict__ C) {
  __shared__ ushort Ts[64][68];
  const int b = blockIdx.y;
  const int tk = blockIdx.x >> 3, ti = blockIdx.x & 7;
  const int k0 = tk * 64, i0 = ti * 64;
  const float* Cb = C + (size_t)b * kN * kN;
  ushort* Ct = g_Ct + (size_t)b * kN * kN;
  const int t = threadIdx.x;
  const int cq = t & 15;
  const int r0 = t >> 4;  // 0..15
#pragma unroll
  for (int p = 0; p < 4; ++p) {
    const int r = r0 + 16 * p;
    const float4 v = *(const float4*)(Cb + (size_t)(k0 + r) * kN + i0 + 4 * cq);
    ushort4 h;
    h.x = f32_to_bf16(v.x); h.y = f32_to_bf16(v.y);
    h.z = f32_to_bf16(v.z); h.w = f32_to_bf16(v.w);
    *(ushort4*)(&Ts[r][4 * cq]) = h;
  }
  __syncthreads();
#pragma unroll
  for (int p = 0; p < 4; ++p) {
    const int r = r0 + 16 * p;
    ushort4 h;
    h.x = Ts[4 * cq + 0][r];
    h.y = Ts[4 * cq + 1][r];
    h.z = Ts[4 * cq + 2][r];
    h.w = Ts[4 * cq + 3][r];
    *(ushort4*)(Ct + (size_t)(i0 + r) * kN + k0 + 4 * cq) = h;
  }
}

// ---------------- build: Q16 = gamma^2 * Ct * Ct^T via bf16 MFMA ----------------
// 128x128 tile/block, 4 waves in 2x2 quadrants, 4x4 16x16 MFMA tiles per wave.
// Fused epilogue also emits fp8(raw acc) for the power phase:
// Q symmetric and mirror tiles accumulate bitwise-identical sums, so each lane packs
// its 4 row-consecutive values into one dword and stores them transposed.

__global__ __launch_bounds__(256) void build_q_kernel(const float* __restrict__ gamma) {
  __shared__ ushort As[128][40];   // [i_local][k_local], pitch 40 halves (16B-aligned rows)
  __shared__ ushort Bs[128][40];
  const int b = blockIdx.y;
  const int ti = blockIdx.x >> 2, tj = blockIdx.x & 3;
  const int i0 = ti * 128, j0 = tj * 128;
  const ushort* Ct = g_Ct + (size_t)b * kN * kN;
  const float gg = gamma[b];
  const float g2 = gg * gg;
  const int t = threadIdx.x;
  const int lane = t & 63, w = t >> 6;
  const int wr = w >> 1, wc = w & 1;
  const int m = lane & 15, q = lane >> 4;
  const int sr = t >> 2;   // 0..63 staging row
  const int ss = t & 3;    // 0..3 staging 8-half segment

  f32x4 acc[4][4];
#pragma unroll
  for (int g = 0; g < 4; ++g)
#pragma unroll
    for (int h = 0; h < 4; ++h) acc[g][h] = (f32x4){0.f, 0.f, 0.f, 0.f};

  for (int k0 = 0; k0 < kN; k0 += 32) {
    const int4 a0 = *(const int4*)(Ct + (size_t)(i0 + sr) * kN + k0 + 8 * ss);
    const int4 a1 = *(const int4*)(Ct + (size_t)(i0 + sr + 64) * kN + k0 + 8 * ss);
    const int4 b0 = *(const int4*)(Ct + (size_t)(j0 + sr) * kN + k0 + 8 * ss);
    const int4 b1 = *(const int4*)(Ct + (size_t)(j0 + sr + 64) * kN + k0 + 8 * ss);
    __syncthreads();
    *(int4*)(&As[sr][8 * ss]) = a0;
    *(int4*)(&As[sr + 64][8 * ss]) = a1;
    *(int4*)(&Bs[sr][8 * ss]) = b0;
    *(int4*)(&Bs[sr + 64][8 * ss]) = b1;
    __syncthreads();
    bf16x8 fa[4], fb[4];
#pragma unroll
    for (int g = 0; g < 4; ++g)
      fa[g] = *(const bf16x8*)(&As[64 * wr + 16 * g + m][8 * q]);
#pragma unroll
    for (int h = 0; h < 4; ++h)
      fb[h] = *(const bf16x8*)(&Bs[64 * wc + 16 * h + m][8 * q]);
#pragma unroll
    for (int g = 0; g < 4; ++g)
#pragma unroll
      for (int h = 0; h < 4; ++h)
        acc[g][h] = __builtin_amdgcn_mfma_f32_16x16x32_bf16(fa[g], fb[h], acc[g][h], 0, 0, 0);
  }

  __half* Qb = g_Q16 + (size_t)b * kN * kN;
  unsigned char* q8b = (unsigned char*)g_Q8 + (size_t)b * kN * kN;
#pragma unroll
  for (int g = 0; g < 4; ++g) {
#pragma unroll
    for (int h = 0; h < 4; ++h) {
      const int col = j0 + 64 * wc + 16 * h + m;
      const int rbase = i0 + 64 * wr + 16 * g + 4 * q;
#pragma unroll
      for (int r = 0; r < 4; ++r)
        Qb[(size_t)(rbase + r) * kN + col] = __float2half(acc[g][h][r] * g2);
      // fp8 of raw (un-scaled) acc, stored transposed: Q8[col][rbase..rbase+3]
      unsigned int pk = 0;
      pk = __builtin_amdgcn_cvt_pk_fp8_f32(acc[g][h][0], acc[g][h][1], pk, false);
      pk = __builtin_amdgcn_cvt_pk_fp8_f32(acc[g][h][2], acc[g][h][3], pk, true);
      *(unsigned int*)(q8b + (size_t)col * kN + rbase) = pk;
    }
  }
}

// ---------------- solver helpers ----------------

__device__ __forceinline__ void fma8(const int4 raw, const float yj, float* acc) {
  const __half2* h2 = reinterpret_cast<const __half2*>(&raw);
#pragma unroll
  for (int k = 0; k < 4; ++k) {
    const float2 f = __half22float2(h2[k]);
    acc[2 * k]     = fmaf(f.x, yj, acc[2 * k]);
    acc[2 * k + 1] = fmaf(f.y, yj, acc[2 * k + 1]);
  }
}

// ---------------- fused per-batch solver ----------------
// Phase 1 (16 waves): fp8 power iteration + fp16 Rayleigh for eta.
// Phase 2 (wave 0 only, ZERO barriers): FISTA with lane-local components 8*lane+c,
// LDS row cache of the active set (prefix-match policy), shuffle-only projection.

__global__ __launch_bounds__(1024) void solver_kernel(const float* __restrict__ rets,
                                                      float* __restrict__ out) {
  __shared__ __align__(16) ushort rowcache[kCacheRows][kN];  // 120 KB; first 32 KB = power partials
  __shared__ float yv_s[kN];
  __shared__ short yi_s[kN];
  __shared__ short cachedrow_s[kCacheRows];
  __shared__ float red_s[8];

  const int t = threadIdx.x;          // 0..1023
  const int lane = t & 63;
  const int w = t >> 6;               // 0..15
  const int b = blockIdx.x;
  const int4* Q16v = (const int4*)(g_Q16 + (size_t)b * kN * kN);
  const uint2* Q8v = (const uint2*)g_Q8 + (size_t)b * (kN * kN / 8);
  float* partial = reinterpret_cast<float*>(&rowcache[0][0]);  // 16*kN floats, power phase only

  // ---- power iteration on fp8 Q (30 iters), normalization folded into matvec ----
  if (t < kN) yv_s[t] = 0.044194173824159216f;  // 1/sqrt(512), already unit norm
  __syncthreads();

  float invn = 1.0f;
  for (int it = 0; it < kPowerIters; ++it) {
    float acc[8] = {0.f, 0.f, 0.f, 0.f, 0.f, 0.f, 0.f, 0.f};
#pragma unroll 8
    for (int k = w; k < kN; k += 16) {
      const uint2 raw = Q8v[(size_t)k * 64 + lane];
      const float yj = yv_s[k];
      acc[0] = fmaf(__builtin_amdgcn_cvt_f32_fp8(raw.x, 0), yj, acc[0]);
      acc[1] = fmaf(__builtin_amdgcn_cvt_f32_fp8(raw.x, 1), yj, acc[1]);
      acc[2] = fmaf(__builtin_amdgcn_cvt_f32_fp8(raw.x, 2), yj, acc[2]);
      acc[3] = fmaf(__builtin_amdgcn_cvt_f32_fp8(raw.x, 3), yj, acc[3]);
      acc[4] = fmaf(__builtin_amdgcn_cvt_f32_fp8(raw.y, 0), yj, acc[4]);
      acc[5] = fmaf(__builtin_amdgcn_cvt_f32_fp8(raw.y, 1), yj, acc[5]);
      acc[6] = fmaf(__builtin_amdgcn_cvt_f32_fp8(raw.y, 2), yj, acc[6]);
      acc[7] = fmaf(__builtin_amdgcn_cvt_f32_fp8(raw.y, 3), yj, acc[7]);
    }
    float4* pp = (float4*)&partial[(w << 9) + (lane << 3)];
    pp[0] = make_float4(acc[0] * invn, acc[1] * invn, acc[2] * invn, acc[3] * invn);
    pp[1] = make_float4(acc[4] * invn, acc[5] * invn, acc[6] * invn, acc[7] * invn);
    __syncthreads();
    if (t < kN) {
      float u = 0.f;
#pragma unroll
      for (int ww = 0; ww < 16; ++ww) u += partial[(ww << 9) + t];
      yv_s[t] = u;                    // unnormalized; next matvec scales by invn
      float qq = u * u;
#pragma unroll
      for (int m2 = 32; m2 > 0; m2 >>= 1) qq += __shfl_xor(qq, m2, 64);
      if (lane == 0) red_s[w] = qq;
    }
    __syncthreads();
    float n2 = 0.f;
#pragma unroll
    for (int i = 0; i < 8; ++i) n2 += red_s[i];
    invn = 1.0f / (sqrtf(n2) + 1e-12f);
  }

  // ---- Rayleigh on fp16 Q: lam = v^T Q v (2nd-order robust to v error) ----
  float eta;
  {
    float acc[8] = {0.f, 0.f, 0.f, 0.f, 0.f, 0.f, 0.f, 0.f};
#pragma unroll 8
    for (int k = w; k < kN; k += 16) {
      const int4 raw = Q16v[(size_t)k * 64 + lane];
      fma8(raw, yv_s[k], acc);
    }
    float4* pp = (float4*)&partial[(w << 9) + (lane << 3)];
    pp[0] = make_float4(acc[0] * invn, acc[1] * invn, acc[2] * invn, acc[3] * invn);
    pp[1] = make_float4(acc[4] * invn, acc[5] * invn, acc[6] * invn, acc[7] * invn);
    __syncthreads();
    if (t < kN) {
      float u = 0.f;
#pragma unroll
      for (int ww = 0; ww < 16; ++ww) u += partial[(ww << 9) + t];
      const float vt = yv_s[t] * invn;
      float ql = vt * u;
#pragma unroll
      for (int m2 = 32; m2 > 0; m2 >>= 1) ql += __shfl_xor(ql, m2, 64);
      if (lane == 0) red_s[w] = ql;
    }
    __syncthreads();
    float lam = 0.f;
#pragma unroll
    for (int i = 0; i < 8; ++i) lam += red_s[i];
    eta = 1.0f / (2.0f * 1.06f * lam + 1e-8f);  // 1.06 safety: fp8 direction noise
  }

  if (w != 0) return;   // waves 1..15 retire; LDS persists for the block

  // ---- FISTA: single wave, zero barriers. Lane owns components 8*lane+c. ----
  float w8[8], y8[8], r8[8];
  {
    const float4 ra = *(const float4*)(rets + (size_t)b * kN + 8 * lane);
    const float4 rc = *(const float4*)(rets + (size_t)b * kN + 8 * lane + 4);
    r8[0] = ra.x; r8[1] = ra.y; r8[2] = ra.z; r8[3] = ra.w;
    r8[4] = rc.x; r8[5] = rc.y; r8[6] = rc.z; r8[7] = rc.w;
  }
#pragma unroll
  for (int c = 0; c < 8; ++c) { w8[c] = 1.0f / 512.0f; y8[c] = 1.0f / 512.0f; }
  for (int k = lane; k < kN; k += 64) { yi_s[k] = (short)k; yv_s[k] = 1.0f / 512.0f; }
  for (int k = lane; k < kCacheRows; k += 64) cachedrow_s[k] = (short)-1;
  int na = kN;
  float tf = 1.0f;

  for (int it = 0; it < kFistaIters; ++it) {
    float acc[8] = {0.f, 0.f, 0.f, 0.f, 0.f, 0.f, 0.f, 0.f};
    const int lim = na < kCacheRows ? na : kCacheRows;

    // matching cache prefix [0,P): compaction order is deterministic, so a stable
    // support keeps the whole prefix hot and the matvec runs entirely from LDS.
    int P = lim;
    for (int k0 = 0; k0 < lim; k0 += 64) {
      const int k = k0 + lane;
      const bool mis = (k < lim) && (cachedrow_s[k] != yi_s[k]);
      const unsigned long long mm = __ballot(mis);
      if (mm) { P = k0 + (int)__ffsll(mm) - 1; break; }
    }

#pragma unroll 8
    for (int k = 0; k < P; ++k)
      fma8(*(const int4*)(&rowcache[k][8 * lane]), yv_s[k], acc);
    for (int k = P; k < lim; ++k) {            // global + refill cache slot k
      const int row = yi_s[k];
      const int4 raw = Q16v[(size_t)row * 64 + lane];
      *(int4*)(&rowcache[k][8 * lane]) = raw;
      if (lane == 0) cachedrow_s[k] = (short)row;
      fma8(raw, yv_s[k], acc);
    }
#pragma unroll 4
    for (int k = lim; k < na; ++k) {           // overflow beyond cache capacity
      const int row = yi_s[k];
      fma8(Q16v[(size_t)row * 64 + lane], yv_s[k], acc);
    }

    float z8[8];
#pragma unroll
    for (int c = 0; c < 8; ++c)
      z8[c] = y8[c] - eta * (2.0f * acc[c] - r8[c]);

    // Michelot projection threshold (shuffle-only)
    float s = 0.f;
#pragma unroll
    for (int c = 0; c < 8; ++c) s += z8[c];
#pragma unroll
    for (int m2 = 32; m2 > 0; m2 >>= 1) s += __shfl_xor(s, m2, 64);
    float theta = (s - 1.0f) * (1.0f / 512.0f);
    int prev = kN;
    for (int r = 0; r < 60; ++r) {
      float ss = 0.f, cc = 0.f;
#pragma unroll
      for (int c = 0; c < 8; ++c)
        if (z8[c] > theta) { ss += z8[c]; cc += 1.0f; }
#pragma unroll
      for (int m2 = 32; m2 > 0; m2 >>= 1) {
        ss += __shfl_xor(ss, m2, 64);
        cc += __shfl_xor(cc, m2, 64);
      }
      const int cnt = (int)(cc + 0.5f);
      if (cnt == prev) break;
      theta = (ss - 1.0f) / cc;
      prev = cnt;
    }

    // update + deterministic compaction (order: c-major, lane-minor; comp = 8*lane+c)
    const float t_new = 0.5f * (1.0f + sqrtf(1.0f + 4.0f * tf * tf));
    const float coef = (tf - 1.0f) / t_new;
    tf = t_new;
    float yn8[8];
    unsigned long long m8[8];
    float dmax = 0.f;
#pragma unroll
    for (int c = 0; c < 8; ++c) {
      const float wn = fmaxf(z8[c] - theta, 0.0f);
      const float yn = wn + coef * (wn - w8[c]);
      dmax = fmaxf(dmax, fmaxf(fabsf(wn - w8[c]), fabsf(yn - y8[c])));
      w8[c] = wn;
      y8[c] = yn;
      yn8[c] = yn;
    }
#pragma unroll
    for (int c = 0; c < 8; ++c) m8[c] = __ballot(yn8[c] != 0.0f);
    int base = 0;
    const unsigned long long lt = (1ull << lane) - 1ull;
#pragma unroll
    for (int c = 0; c < 8; ++c) {
      if (yn8[c] != 0.0f) {
        const int pos = base + __popcll(m8[c] & lt);
        yi_s[pos] = (short)(8 * lane + c);
        yv_s[pos] = yn8[c];
      }
      base += __popcll(m8[c]);
    }
    na = base;
#pragma unroll
    for (int m2 = 32; m2 > 0; m2 >>= 1) dmax = fmaxf(dmax, __shfl_xor(dmax, m2, 64));
    if (dmax < 1e-7f) break;   // numerical fixed point: rest of iters are no-ops
  }

  *(float4*)(out + (size_t)b * kN + 8 * lane)     = make_float4(w8[0], w8[1], w8[2], w8[3]);
  *(float4*)(out + (size_t)b * kN + 8 * lane + 4) = make_float4(w8[4], w8[5], w8[6], w8[7]);
}

extern "C" void kernel_launch(void* const* d_in, const int* in_sizes, int n_in,
                              void* d_out, int out_size, void* d_ws, size_t ws_size,
                              hipStream_t stream) {
  (void)in_sizes; (void)n_in; (void)out_size; (void)d_ws; (void)ws_size;
  const float* rets  = (const float*)d_in[0];
  const float* cov   = (const float*)d_in[1];
  const float* gamma = (const float*)d_in[2];
  float* out = (float*)d_out;

  transpose_kernel<<<dim3(64, kB), 256, 0, stream>>>(cov);
  build_q_kernel<<<dim3(16, kB), 256, 0, stream>>>(gamma);
  solver_kernel<<<kB, 1024, 0, stream>>>(rets, out);
}

// Round 3
// 2057.390 us; speedup vs baseline: 1.0664x; 1.0321x over previous
//
#include <hip/hip_runtime.h>
#include <hip/hip_fp16.h>

namespace {
constexpr int kN = 512;
constexpr int kB = 256;
constexpr int kPowerIters = 30;
constexpr int kFistaIters = 300;
constexpr int kCacheRows = 120;   // 120 KB LDS row cache (fp16 rows of Q)
}

typedef __attribute__((ext_vector_type(8))) short bf16x8;
typedef __attribute__((ext_vector_type(4))) float f32x4;

// Device-global scratch (BSS): ignore d_ws entirely. All fully rewritten each call.
__device__ ushort g_Ct[(size_t)kB * kN * kN];          // bf16 C^T, 128 MiB
__device__ __half g_Q16[(size_t)kB * kN * kN];         // fp16 Q (gamma^2-scaled), 128 MiB
__device__ unsigned int g_Q8[(size_t)kB * kN * kN / 4];// fp8 e4m3 of Q/gamma^2, 64 MiB

// ---------------- transpose: C[b][k][i] fp32 -> Ct[b][i][k] bf16 ----------------

__device__ __forceinline__ ushort f32_to_bf16(float f) {
  unsigned int u = __float_as_uint(f);
  unsigned int r = u + 0x7FFFu + ((u >> 16) & 1u);   // RNE
  return (ushort)(r >> 16);
}

__global__ __launch_bounds__(256) void transpose_kernel(const float* __restrict__ C) {
  __shared__ ushort Ts[64][68];
  const int b = blockIdx.y;
  const int tk = blockIdx.x >> 3, ti = blockIdx.x & 7;
  const int k0 = tk * 64, i0 = ti * 64;
  const float* Cb = C + (size_t)b * kN * kN;
  ushort* Ct = g_Ct + (size_t)b * kN * kN;
  const int t = threadIdx.x;
  const int cq = t & 15;
  const int r0 = t >> 4;  // 0..15
#pragma unroll
  for (int p = 0; p < 4; ++p) {
    const int r = r0 + 16 * p;
    const float4 v = *(const float4*)(Cb + (size_t)(k0 + r) * kN + i0 + 4 * cq);
    ushort4 h;
    h.x = f32_to_bf16(v.x); h.y = f32_to_bf16(v.y);
    h.z = f32_to_bf16(v.z); h.w = f32_to_bf16(v.w);
    *(ushort4*)(&Ts[r][4 * cq]) = h;
  }
  __syncthreads();
#pragma unroll
  for (int p = 0; p < 4; ++p) {
    const int r = r0 + 16 * p;
    ushort4 h;
    h.x = Ts[4 * cq + 0][r];
    h.y = Ts[4 * cq + 1][r];
    h.z = Ts[4 * cq + 2][r];
    h.w = Ts[4 * cq + 3][r];
    *(ushort4*)(Ct + (size_t)(i0 + r) * kN + k0 + 4 * cq) = h;
  }
}

// ---------------- build: Q16 = gamma^2 * Ct * Ct^T via bf16 MFMA ----------------
// 128x128 tile/block, 4 waves in 2x2 quadrants, 4x4 16x16 MFMA tiles per wave.
// Fused epilogue also emits fp8(raw acc) for the power phase:
// Q symmetric and mirror tiles accumulate bitwise-identical sums, so each lane packs
// its 4 row-consecutive values into one dword and stores them transposed.

__global__ __launch_bounds__(256) void build_q_kernel(const float* __restrict__ gamma) {
  __shared__ ushort As[128][40];   // [i_local][k_local], pitch 40 halves (16B-aligned rows)
  __shared__ ushort Bs[128][40];
  const int b = blockIdx.y;
  const int ti = blockIdx.x >> 2, tj = blockIdx.x & 3;
  const int i0 = ti * 128, j0 = tj * 128;
  const ushort* Ct = g_Ct + (size_t)b * kN * kN;
  const float gg = gamma[b];
  const float g2 = gg * gg;
  const int t = threadIdx.x;
  const int lane = t & 63, w = t >> 6;
  const int wr = w >> 1, wc = w & 1;
  const int m = lane & 15, q = lane >> 4;
  const int sr = t >> 2;   // 0..63 staging row
  const int ss = t & 3;    // 0..3 staging 8-half segment

  f32x4 acc[4][4];
#pragma unroll
  for (int g = 0; g < 4; ++g)
#pragma unroll
    for (int h = 0; h < 4; ++h) acc[g][h] = (f32x4){0.f, 0.f, 0.f, 0.f};

  for (int k0 = 0; k0 < kN; k0 += 32) {
    const int4 a0 = *(const int4*)(Ct + (size_t)(i0 + sr) * kN + k0 + 8 * ss);
    const int4 a1 = *(const int4*)(Ct + (size_t)(i0 + sr + 64) * kN + k0 + 8 * ss);
    const int4 b0 = *(const int4*)(Ct + (size_t)(j0 + sr) * kN + k0 + 8 * ss);
    const int4 b1 = *(const int4*)(Ct + (size_t)(j0 + sr + 64) * kN + k0 + 8 * ss);
    __syncthreads();
    *(int4*)(&As[sr][8 * ss]) = a0;
    *(int4*)(&As[sr + 64][8 * ss]) = a1;
    *(int4*)(&Bs[sr][8 * ss]) = b0;
    *(int4*)(&Bs[sr + 64][8 * ss]) = b1;
    __syncthreads();
    bf16x8 fa[4], fb[4];
#pragma unroll
    for (int g = 0; g < 4; ++g)
      fa[g] = *(const bf16x8*)(&As[64 * wr + 16 * g + m][8 * q]);
#pragma unroll
    for (int h = 0; h < 4; ++h)
      fb[h] = *(const bf16x8*)(&Bs[64 * wc + 16 * h + m][8 * q]);
#pragma unroll
    for (int g = 0; g < 4; ++g)
#pragma unroll
      for (int h = 0; h < 4; ++h)
        acc[g][h] = __builtin_amdgcn_mfma_f32_16x16x32_bf16(fa[g], fb[h], acc[g][h], 0, 0, 0);
  }

  __half* Qb = g_Q16 + (size_t)b * kN * kN;
  unsigned char* q8b = (unsigned char*)g_Q8 + (size_t)b * kN * kN;
#pragma unroll
  for (int g = 0; g < 4; ++g) {
#pragma unroll
    for (int h = 0; h < 4; ++h) {
      const int col = j0 + 64 * wc + 16 * h + m;
      const int rbase = i0 + 64 * wr + 16 * g + 4 * q;
#pragma unroll
      for (int r = 0; r < 4; ++r)
        Qb[(size_t)(rbase + r) * kN + col] = __float2half(acc[g][h][r] * g2);
      // fp8 of raw (un-scaled) acc, stored transposed: Q8[col][rbase..rbase+3]
      unsigned int pk = 0;
      pk = __builtin_amdgcn_cvt_pk_fp8_f32(acc[g][h][0], acc[g][h][1], pk, false);
      pk = __builtin_amdgcn_cvt_pk_fp8_f32(acc[g][h][2], acc[g][h][3], pk, true);
      *(unsigned int*)(q8b + (size_t)col * kN + rbase) = pk;
    }
  }
}

// ---------------- solver helpers ----------------

__device__ __forceinline__ void fma8(const int4 raw, const float yj, float* acc) {
  const __half2* h2 = reinterpret_cast<const __half2*>(&raw);
#pragma unroll
  for (int k = 0; k < 4; ++k) {
    const float2 f = __half22float2(h2[k]);
    acc[2 * k]     = fmaf(f.x, yj, acc[2 * k]);
    acc[2 * k + 1] = fmaf(f.y, yj, acc[2 * k + 1]);
  }
}

// Simplex projection (Michelot) + FISTA momentum + deterministic compaction.
// Whole wave participates. Returns new active count; dmax is wave-uniform on return.
// Component mapping: comp = 8*lane + c. Compaction order: c-major, lane-minor.
__device__ __forceinline__ int fista_proj_update(const float z8[8], float w8[8], float y8[8],
                                                 float& tf, float* yv_s, short* yi_s,
                                                 float& dmax_out) {
  const int lane = threadIdx.x & 63;
  float s = 0.f;
#pragma unroll
  for (int c = 0; c < 8; ++c) s += z8[c];
#pragma unroll
  for (int m2 = 32; m2 > 0; m2 >>= 1) s += __shfl_xor(s, m2, 64);
  float theta = (s - 1.0f) * (1.0f / 512.0f);
  int prev = kN;
  for (int r = 0; r < 60; ++r) {
    float ss = 0.f, cc = 0.f;
#pragma unroll
    for (int c = 0; c < 8; ++c)
      if (z8[c] > theta) { ss += z8[c]; cc += 1.0f; }
#pragma unroll
    for (int m2 = 32; m2 > 0; m2 >>= 1) {
      ss += __shfl_xor(ss, m2, 64);
      cc += __shfl_xor(cc, m2, 64);
    }
    const int cnt = (int)(cc + 0.5f);
    if (cnt == prev) break;
    theta = (ss - 1.0f) / cc;
    prev = cnt;
  }

  const float t_new = 0.5f * (1.0f + sqrtf(1.0f + 4.0f * tf * tf));
  const float coef = (tf - 1.0f) / t_new;
  tf = t_new;
  float yn8[8];
  unsigned long long m8[8];
  float dmax = 0.f;
#pragma unroll
  for (int c = 0; c < 8; ++c) {
    const float wn = fmaxf(z8[c] - theta, 0.0f);
    const float yn = wn + coef * (wn - w8[c]);
    dmax = fmaxf(dmax, fmaxf(fabsf(wn - w8[c]), fabsf(yn - y8[c])));
    w8[c] = wn;
    y8[c] = yn;
    yn8[c] = yn;
  }
#pragma unroll
  for (int c = 0; c < 8; ++c) m8[c] = __ballot(yn8[c] != 0.0f);
  int base = 0;
  const unsigned long long lt = (1ull << lane) - 1ull;
#pragma unroll
  for (int c = 0; c < 8; ++c) {
    if (yn8[c] != 0.0f) {
      const int pos = base + __popcll(m8[c] & lt);
      yi_s[pos] = (short)(8 * lane + c);
      yv_s[pos] = yn8[c];
    }
    base += __popcll(m8[c]);
  }
#pragma unroll
  for (int m2 = 32; m2 > 0; m2 >>= 1) dmax = fmaxf(dmax, __shfl_xor(dmax, m2, 64));
  dmax_out = dmax;
  return base;
}

// ---------------- fused per-batch solver ----------------
// Phase 1 (16 waves): fp8 power iteration + fp16 Rayleigh for eta.
// Phase A (16 waves, na > kCacheRows): heavy iterations — matvec split across 16 waves
//   (16x memory parallelism for the HBM-latency-bound dense gathers), wave0 projection.
// Switch: cooperative fill of the LDS row cache with the whole active support.
// Phase B (wave 0 only, ZERO barriers): sparse tail from LDS cache, prefix-match policy.

__global__ __launch_bounds__(1024) void solver_kernel(const float* __restrict__ rets,
                                                      float* __restrict__ out) {
  __shared__ __align__(16) ushort rowcache[kCacheRows][kN];  // 120 KB; first 32 KB = partials
  __shared__ __align__(16) float yv_s[kN];
  __shared__ __align__(16) float zred_s[kN];
  __shared__ short yi_s[kN];
  __shared__ short cachedrow_s[kCacheRows];
  __shared__ float red_s[8];
  __shared__ int nact_s;
  __shared__ int done_s;

  const int t = threadIdx.x;          // 0..1023
  const int lane = t & 63;
  const int w = t >> 6;               // 0..15
  const int b = blockIdx.x;
  const int4* Q16v = (const int4*)(g_Q16 + (size_t)b * kN * kN);
  const uint2* Q8v = (const uint2*)g_Q8 + (size_t)b * (kN * kN / 8);
  float* partial = reinterpret_cast<float*>(&rowcache[0][0]);  // 16*kN floats (phases 1/A only)

  // ---- power iteration on fp8 Q (30 iters), normalization folded into matvec ----
  if (t < kN) yv_s[t] = 0.044194173824159216f;  // 1/sqrt(512), already unit norm
  if (t == 0) done_s = 0;
  __syncthreads();

  float invn = 1.0f;
  for (int it = 0; it < kPowerIters; ++it) {
    float acc[8] = {0.f, 0.f, 0.f, 0.f, 0.f, 0.f, 0.f, 0.f};
#pragma unroll 8
    for (int k = w; k < kN; k += 16) {
      const uint2 raw = Q8v[(size_t)k * 64 + lane];
      const float yj = yv_s[k];
      acc[0] = fmaf(__builtin_amdgcn_cvt_f32_fp8(raw.x, 0), yj, acc[0]);
      acc[1] = fmaf(__builtin_amdgcn_cvt_f32_fp8(raw.x, 1), yj, acc[1]);
      acc[2] = fmaf(__builtin_amdgcn_cvt_f32_fp8(raw.x, 2), yj, acc[2]);
      acc[3] = fmaf(__builtin_amdgcn_cvt_f32_fp8(raw.x, 3), yj, acc[3]);
      acc[4] = fmaf(__builtin_amdgcn_cvt_f32_fp8(raw.y, 0), yj, acc[4]);
      acc[5] = fmaf(__builtin_amdgcn_cvt_f32_fp8(raw.y, 1), yj, acc[5]);
      acc[6] = fmaf(__builtin_amdgcn_cvt_f32_fp8(raw.y, 2), yj, acc[6]);
      acc[7] = fmaf(__builtin_amdgcn_cvt_f32_fp8(raw.y, 3), yj, acc[7]);
    }
    float4* pp = (float4*)&partial[(w << 9) + (lane << 3)];
    pp[0] = make_float4(acc[0] * invn, acc[1] * invn, acc[2] * invn, acc[3] * invn);
    pp[1] = make_float4(acc[4] * invn, acc[5] * invn, acc[6] * invn, acc[7] * invn);
    __syncthreads();
    if (t < kN) {
      float u = 0.f;
#pragma unroll
      for (int ww = 0; ww < 16; ++ww) u += partial[(ww << 9) + t];
      yv_s[t] = u;                    // unnormalized; next matvec scales by invn
      float qq = u * u;
#pragma unroll
      for (int m2 = 32; m2 > 0; m2 >>= 1) qq += __shfl_xor(qq, m2, 64);
      if (lane == 0) red_s[w] = qq;
    }
    __syncthreads();
    float n2 = 0.f;
#pragma unroll
    for (int i = 0; i < 8; ++i) n2 += red_s[i];
    invn = 1.0f / (sqrtf(n2) + 1e-12f);
  }

  // ---- Rayleigh on fp16 Q: lam = v^T Q v (2nd-order robust to v error) ----
  float eta;
  {
    float acc[8] = {0.f, 0.f, 0.f, 0.f, 0.f, 0.f, 0.f, 0.f};
#pragma unroll 8
    for (int k = w; k < kN; k += 16) {
      const int4 raw = Q16v[(size_t)k * 64 + lane];
      fma8(raw, yv_s[k], acc);
    }
    float4* pp = (float4*)&partial[(w << 9) + (lane << 3)];
    pp[0] = make_float4(acc[0] * invn, acc[1] * invn, acc[2] * invn, acc[3] * invn);
    pp[1] = make_float4(acc[4] * invn, acc[5] * invn, acc[6] * invn, acc[7] * invn);
    __syncthreads();
    if (t < kN) {
      float u = 0.f;
#pragma unroll
      for (int ww = 0; ww < 16; ++ww) u += partial[(ww << 9) + t];
      const float vt = yv_s[t] * invn;
      float ql = vt * u;
#pragma unroll
      for (int m2 = 32; m2 > 0; m2 >>= 1) ql += __shfl_xor(ql, m2, 64);
      if (lane == 0) red_s[w] = ql;
    }
    __syncthreads();
    float lam = 0.f;
#pragma unroll
    for (int i = 0; i < 8; ++i) lam += red_s[i];
    eta = 1.0f / (2.0f * 1.06f * lam + 1e-8f);  // 1.06 safety: fp8 direction noise
  }

  // ---- FISTA init: comp = 8*lane+c on wave0; yi/yv dense ----
  float w8[8], y8[8], r8[8];
  float tf = 1.0f;
  if (t < kN) { yv_s[t] = 1.0f / 512.0f; yi_s[t] = (short)t; }
  if (t == 0) nact_s = kN;
  if (w == 0) {
    const float4 ra = *(const float4*)(rets + (size_t)b * kN + 8 * lane);
    const float4 rc = *(const float4*)(rets + (size_t)b * kN + 8 * lane + 4);
    r8[0] = ra.x; r8[1] = ra.y; r8[2] = ra.z; r8[3] = ra.w;
    r8[4] = rc.x; r8[5] = rc.y; r8[6] = rc.z; r8[7] = rc.w;
#pragma unroll
    for (int c = 0; c < 8; ++c) { w8[c] = 1.0f / 512.0f; y8[c] = 1.0f / 512.0f; }
  }
  __syncthreads();

  // ---- Phase A: 16-wave iterations while the support is large ----
  int it = 0;
  for (; it < kFistaIters; ++it) {
    const int na = nact_s;
    if (na <= kCacheRows || done_s) break;
    float acc[8] = {0.f, 0.f, 0.f, 0.f, 0.f, 0.f, 0.f, 0.f};
#pragma unroll 8
    for (int k = w; k < na; k += 16) {
      const int row = yi_s[k];
      fma8(Q16v[(size_t)row * 64 + lane], yv_s[k], acc);
    }
    float4* pp = (float4*)&partial[(w << 9) + (lane << 3)];
    pp[0] = make_float4(acc[0], acc[1], acc[2], acc[3]);
    pp[1] = make_float4(acc[4], acc[5], acc[6], acc[7]);
    __syncthreads();
    if (t < kN) {
      float u = 0.f;
#pragma unroll
      for (int ww = 0; ww < 16; ++ww) u += partial[(ww << 9) + t];
      zred_s[t] = u;
    }
    __syncthreads();
    if (w == 0) {
      float z8[8];
      const float4 za = *(const float4*)&zred_s[8 * lane];
      const float4 zb = *(const float4*)&zred_s[8 * lane + 4];
      z8[0] = y8[0] - eta * (2.0f * za.x - r8[0]);
      z8[1] = y8[1] - eta * (2.0f * za.y - r8[1]);
      z8[2] = y8[2] - eta * (2.0f * za.z - r8[2]);
      z8[3] = y8[3] - eta * (2.0f * za.w - r8[3]);
      z8[4] = y8[4] - eta * (2.0f * zb.x - r8[4]);
      z8[5] = y8[5] - eta * (2.0f * zb.y - r8[5]);
      z8[6] = y8[6] - eta * (2.0f * zb.z - r8[6]);
      z8[7] = y8[7] - eta * (2.0f * zb.w - r8[7]);
      float dmax;
      const int nb = fista_proj_update(z8, w8, y8, tf, yv_s, yi_s, dmax);
      if (lane == 0) {
        nact_s = nb;
        if (dmax < 1e-7f) done_s = 1;
      }
    }
    __syncthreads();
  }

  const bool finished = (done_s != 0) || (it >= kFistaIters);
  if (!finished) {
    // cooperative cache fill: whole active support -> LDS (16 waves)
    const int naf = nact_s;
    for (int k = w; k < naf; k += 16)
      *(int4*)(&rowcache[k][8 * lane]) = Q16v[(size_t)yi_s[k] * 64 + lane];
    if (t < kCacheRows) cachedrow_s[t] = (t < naf) ? yi_s[t] : (short)-1;
    __syncthreads();
  }
  if (w != 0) return;   // waves 1..15 retire; LDS persists for the block

  if (!finished) {
    // ---- Phase B: single wave, zero barriers ----
    int na = nact_s;
    for (; it < kFistaIters; ++it) {
      float acc[8] = {0.f, 0.f, 0.f, 0.f, 0.f, 0.f, 0.f, 0.f};
      const int lim = na < kCacheRows ? na : kCacheRows;

      // matching cache prefix [0,P): compaction order is deterministic, so a stable
      // support keeps the whole prefix hot and the matvec runs entirely from LDS.
      int P = lim;
      for (int k0 = 0; k0 < lim; k0 += 64) {
        const int k = k0 + lane;
        const bool mis = (k < lim) && (cachedrow_s[k] != yi_s[k]);
        const unsigned long long mm = __ballot(mis);
        if (mm) { P = k0 + (int)__ffsll(mm) - 1; break; }
      }

#pragma unroll 8
      for (int k = 0; k < P; ++k)
        fma8(*(const int4*)(&rowcache[k][8 * lane]), yv_s[k], acc);
      for (int k = P; k < lim; ++k) {            // global + refill cache slot k
        const int row = yi_s[k];
        const int4 raw = Q16v[(size_t)row * 64 + lane];
        *(int4*)(&rowcache[k][8 * lane]) = raw;
        if (lane == 0) cachedrow_s[k] = (short)row;
        fma8(raw, yv_s[k], acc);
      }
#pragma unroll 4
      for (int k = lim; k < na; ++k) {           // overflow beyond cache capacity
        const int row = yi_s[k];
        fma8(Q16v[(size_t)row * 64 + lane], yv_s[k], acc);
      }

      float z8[8];
#pragma unroll
      for (int c = 0; c < 8; ++c)
        z8[c] = y8[c] - eta * (2.0f * acc[c] - r8[c]);

      float dmax;
      na = fista_proj_update(z8, w8, y8, tf, yv_s, yi_s, dmax);
      if (dmax < 1e-7f) break;   // numerical fixed point: rest of iters are no-ops
    }
  }

  *(float4*)(out + (size_t)b * kN + 8 * lane)     = make_float4(w8[0], w8[1], w8[2], w8[3]);
  *(float4*)(out + (size_t)b * kN + 8 * lane + 4) = make_float4(w8[4], w8[5], w8[6], w8[7]);
}

extern "C" void kernel_launch(void* const* d_in, const int* in_sizes, int n_in,
                              void* d_out, int out_size, void* d_ws, size_t ws_size,
                              hipStream_t stream) {
  (void)in_sizes; (void)n_in; (void)out_size; (void)d_ws; (void)ws_size;
  const float* rets  = (const float*)d_in[0];
  const float* cov   = (const float*)d_in[1];
  const float* gamma = (const float*)d_in[2];
  float* out = (float*)d_out;

  transpose_kernel<<<dim3(64, kB), 256, 0, stream>>>(cov);
  build_q_kernel<<<dim3(16, kB), 256, 0, stream>>>(gamma);
  solver_kernel<<<kB, 1024, 0, stream>>>(rets, out);
}

// Round 4
// 1433.091 us; speedup vs baseline: 1.5310x; 1.4356x over previous
//
#include <hip/hip_runtime.h>
#include <hip/hip_fp16.h>

namespace {
constexpr int kN = 512;
constexpr int kB = 256;
constexpr int kPowerIters = 30;
constexpr int kFistaIters = 300;
constexpr int kCacheRows = 120;   // 120 KB LDS row cache (fp16 rows of Q)
}

typedef __attribute__((ext_vector_type(8))) short bf16x8;
typedef __attribute__((ext_vector_type(4))) float f32x4;

// Device-global scratch (BSS): ignore d_ws entirely. All fully rewritten each call.
__device__ ushort g_Ct[(size_t)kB * kN * kN];          // bf16 C^T, 128 MiB
__device__ __half g_Q16[(size_t)kB * kN * kN];         // fp16 Q (gamma^2-scaled), 128 MiB
__device__ unsigned int g_Q8[(size_t)kB * kN * kN / 4];// fp8 e4m3 of Q/gamma^2, 64 MiB

// ---------------- fast wave reductions ----------------
// Same pairing order as the old shfl_xor butterfly (32,16,8,4,2,1) -> bit-identical
// sums; levels 8/2/1 use DPP (VALU latency) and 4 uses ds_swizzle, cutting the
// dependent chain from 6 ds-ops to 3.
__device__ __forceinline__ float wave_sum64(float x) {
  x += __shfl_xor(x, 32, 64);
  x += __shfl_xor(x, 16, 64);
  x += __int_as_float(__builtin_amdgcn_update_dpp(0, __float_as_int(x), 0x128, 0xF, 0xF, true)); // row_ror:8 == xor8
  x += __int_as_float(__builtin_amdgcn_ds_swizzle(__float_as_int(x), 0x101F));                    // xor4
  x += __int_as_float(__builtin_amdgcn_update_dpp(0, __float_as_int(x), 0x4E, 0xF, 0xF, true));   // quad_perm xor2
  x += __int_as_float(__builtin_amdgcn_update_dpp(0, __float_as_int(x), 0xB1, 0xF, 0xF, true));   // quad_perm xor1
  return x;
}
__device__ __forceinline__ float wave_max64(float x) {
  x = fmaxf(x, __shfl_xor(x, 32, 64));
  x = fmaxf(x, __shfl_xor(x, 16, 64));
  x = fmaxf(x, __int_as_float(__builtin_amdgcn_update_dpp(0, __float_as_int(x), 0x128, 0xF, 0xF, true)));
  x = fmaxf(x, __int_as_float(__builtin_amdgcn_ds_swizzle(__float_as_int(x), 0x101F)));
  x = fmaxf(x, __int_as_float(__builtin_amdgcn_update_dpp(0, __float_as_int(x), 0x4E, 0xF, 0xF, true)));
  x = fmaxf(x, __int_as_float(__builtin_amdgcn_update_dpp(0, __float_as_int(x), 0xB1, 0xF, 0xF, true)));
  return x;
}

// ---------------- transpose: C[b][k][i] fp32 -> Ct[b][i][k] bf16 ----------------

__device__ __forceinline__ ushort f32_to_bf16(float f) {
  unsigned int u = __float_as_uint(f);
  unsigned int r = u + 0x7FFFu + ((u >> 16) & 1u);   // RNE
  return (ushort)(r >> 16);
}

__global__ __launch_bounds__(256) void transpose_kernel(const float* __restrict__ C) {
  __shared__ ushort Ts[64][68];
  const int b = blockIdx.y;
  const int tk = blockIdx.x >> 3, ti = blockIdx.x & 7;
  const int k0 = tk * 64, i0 = ti * 64;
  const float* Cb = C + (size_t)b * kN * kN;
  ushort* Ct = g_Ct + (size_t)b * kN * kN;
  const int t = threadIdx.x;
  const int cq = t & 15;
  const int r0 = t >> 4;  // 0..15
#pragma unroll
  for (int p = 0; p < 4; ++p) {
    const int r = r0 + 16 * p;
    const float4 v = *(const float4*)(Cb + (size_t)(k0 + r) * kN + i0 + 4 * cq);
    ushort4 h;
    h.x = f32_to_bf16(v.x); h.y = f32_to_bf16(v.y);
    h.z = f32_to_bf16(v.z); h.w = f32_to_bf16(v.w);
    *(ushort4*)(&Ts[r][4 * cq]) = h;
  }
  __syncthreads();
#pragma unroll
  for (int p = 0; p < 4; ++p) {
    const int r = r0 + 16 * p;
    ushort4 h;
    h.x = Ts[4 * cq + 0][r];
    h.y = Ts[4 * cq + 1][r];
    h.z = Ts[4 * cq + 2][r];
    h.w = Ts[4 * cq + 3][r];
    *(ushort4*)(Ct + (size_t)(i0 + r) * kN + k0 + 4 * cq) = h;
  }
}

// ---------------- build: Q16 = gamma^2 * Ct * Ct^T via bf16 MFMA ----------------
// 128x128 tile/block, 4 waves in 2x2 quadrants, 4x4 16x16 MFMA tiles per wave.
// Fused epilogue also emits fp8(raw acc) for the power phase:
// Q symmetric and mirror tiles accumulate bitwise-identical sums, so each lane packs
// its 4 row-consecutive values into one dword and stores them transposed.

__global__ __launch_bounds__(256) void build_q_kernel(const float* __restrict__ gamma) {
  __shared__ ushort As[128][40];   // [i_local][k_local], pitch 40 halves (16B-aligned rows)
  __shared__ ushort Bs[128][40];
  const int b = blockIdx.y;
  const int ti = blockIdx.x >> 2, tj = blockIdx.x & 3;
  const int i0 = ti * 128, j0 = tj * 128;
  const ushort* Ct = g_Ct + (size_t)b * kN * kN;
  const float gg = gamma[b];
  const float g2 = gg * gg;
  const int t = threadIdx.x;
  const int lane = t & 63, w = t >> 6;
  const int wr = w >> 1, wc = w & 1;
  const int m = lane & 15, q = lane >> 4;
  const int sr = t >> 2;   // 0..63 staging row
  const int ss = t & 3;    // 0..3 staging 8-half segment

  f32x4 acc[4][4];
#pragma unroll
  for (int g = 0; g < 4; ++g)
#pragma unroll
    for (int h = 0; h < 4; ++h) acc[g][h] = (f32x4){0.f, 0.f, 0.f, 0.f};

  for (int k0 = 0; k0 < kN; k0 += 32) {
    const int4 a0 = *(const int4*)(Ct + (size_t)(i0 + sr) * kN + k0 + 8 * ss);
    const int4 a1 = *(const int4*)(Ct + (size_t)(i0 + sr + 64) * kN + k0 + 8 * ss);
    const int4 b0 = *(const int4*)(Ct + (size_t)(j0 + sr) * kN + k0 + 8 * ss);
    const int4 b1 = *(const int4*)(Ct + (size_t)(j0 + sr + 64) * kN + k0 + 8 * ss);
    __syncthreads();
    *(int4*)(&As[sr][8 * ss]) = a0;
    *(int4*)(&As[sr + 64][8 * ss]) = a1;
    *(int4*)(&Bs[sr][8 * ss]) = b0;
    *(int4*)(&Bs[sr + 64][8 * ss]) = b1;
    __syncthreads();
    bf16x8 fa[4], fb[4];
#pragma unroll
    for (int g = 0; g < 4; ++g)
      fa[g] = *(const bf16x8*)(&As[64 * wr + 16 * g + m][8 * q]);
#pragma unroll
    for (int h = 0; h < 4; ++h)
      fb[h] = *(const bf16x8*)(&Bs[64 * wc + 16 * h + m][8 * q]);
#pragma unroll
    for (int g = 0; g < 4; ++g)
#pragma unroll
      for (int h = 0; h < 4; ++h)
        acc[g][h] = __builtin_amdgcn_mfma_f32_16x16x32_bf16(fa[g], fb[h], acc[g][h], 0, 0, 0);
  }

  __half* Qb = g_Q16 + (size_t)b * kN * kN;
  unsigned char* q8b = (unsigned char*)g_Q8 + (size_t)b * kN * kN;
#pragma unroll
  for (int g = 0; g < 4; ++g) {
#pragma unroll
    for (int h = 0; h < 4; ++h) {
      const int col = j0 + 64 * wc + 16 * h + m;
      const int rbase = i0 + 64 * wr + 16 * g + 4 * q;
#pragma unroll
      for (int r = 0; r < 4; ++r)
        Qb[(size_t)(rbase + r) * kN + col] = __float2half(acc[g][h][r] * g2);
      // fp8 of raw (un-scaled) acc, stored transposed: Q8[col][rbase..rbase+3]
      unsigned int pk = 0;
      pk = __builtin_amdgcn_cvt_pk_fp8_f32(acc[g][h][0], acc[g][h][1], pk, false);
      pk = __builtin_amdgcn_cvt_pk_fp8_f32(acc[g][h][2], acc[g][h][3], pk, true);
      *(unsigned int*)(q8b + (size_t)col * kN + rbase) = pk;
    }
  }
}

// ---------------- solver helpers ----------------

__device__ __forceinline__ void fma8(const int4 raw, const float yj, float* acc) {
  const __half2* h2 = reinterpret_cast<const __half2*>(&raw);
#pragma unroll
  for (int k = 0; k < 4; ++k) {
    const float2 f = __half22float2(h2[k]);
    acc[2 * k]     = fmaf(f.x, yj, acc[2 * k]);
    acc[2 * k + 1] = fmaf(f.y, yj, acc[2 * k + 1]);
  }
}

// Simplex projection (Michelot, WARM-STARTED) + FISTA momentum + deterministic
// compaction. Whole wave participates. Returns new active count; dmax and theta_io
// are wave-uniform on return; m8_out gets the 8 compaction ballots (uniform).
// Warm start is Newton on the convex piecewise-linear f(theta)=sum(max(z-theta,0))-1:
// from any start, one step lands <= theta*, then monotone finite convergence; the
// exiting theta is (sum_{A*}z-1)/|A*| -- identical to cold start at stable support.
// Component mapping: comp = 8*lane + c. Compaction order: c-major, lane-minor.
__device__ __forceinline__ int fista_proj_update(const float z8[8], float w8[8], float y8[8],
                                                 float& tf, float& theta_io,
                                                 float* yv_s, short* yi_s,
                                                 unsigned long long m8_out[8],
                                                 float& dmax_out) {
  const int lane = threadIdx.x & 63;
  float theta = theta_io;
  int prev = -1;
  for (int r = 0; r < 60; ++r) {
    float ss = 0.f, cc = 0.f;
#pragma unroll
    for (int c = 0; c < 8; ++c)
      if (z8[c] > theta) { ss += z8[c]; cc += 1.0f; }
    ss = wave_sum64(ss);
    cc = wave_sum64(cc);
    const int cnt = (int)(cc + 0.5f);
    if (cnt == 0) {                 // degenerate warm start: cold restart (then nonempty)
      float s = 0.f;
#pragma unroll
      for (int c = 0; c < 8; ++c) s += z8[c];
      s = wave_sum64(s);
      theta = (s - 1.0f) * (1.0f / 512.0f);
      prev = -1;
      continue;
    }
    if (cnt == prev) break;
    theta = (ss - 1.0f) / cc;
    prev = cnt;
  }
  theta_io = theta;

  const float t_new = 0.5f * (1.0f + sqrtf(1.0f + 4.0f * tf * tf));
  const float coef = (tf - 1.0f) / t_new;
  tf = t_new;
  float yn8[8];
  float dmax = 0.f;
#pragma unroll
  for (int c = 0; c < 8; ++c) {
    const float wn = fmaxf(z8[c] - theta, 0.0f);
    const float yn = wn + coef * (wn - w8[c]);
    dmax = fmaxf(dmax, fmaxf(fabsf(wn - w8[c]), fabsf(yn - y8[c])));
    w8[c] = wn;
    y8[c] = yn;
    yn8[c] = yn;
  }
#pragma unroll
  for (int c = 0; c < 8; ++c) m8_out[c] = __ballot(yn8[c] != 0.0f);
  int base = 0;
  const unsigned long long lt = (1ull << lane) - 1ull;
#pragma unroll
  for (int c = 0; c < 8; ++c) {
    if (yn8[c] != 0.0f) {
      const int pos = base + __popcll(m8_out[c] & lt);
      yi_s[pos] = (short)(8 * lane + c);
      yv_s[pos] = yn8[c];
    }
    base += __popcll(m8_out[c]);
  }
  dmax_out = wave_max64(dmax);
  return base;
}

// ---------------- fused per-batch solver ----------------
// Phase 1 (16 waves): fp8 power iteration + fp16 Rayleigh for eta.
// Phase A (16 waves, na > kCacheRows): heavy iterations — matvec split across 16 waves,
//   wave0 projection (warm-started Michelot).
// Switch: cooperative fill of the LDS row cache with the whole active support.
// Phase B (wave 0 only, ZERO barriers): sparse tail from LDS cache; prefix scan is
//   skipped entirely when the compaction ballots are unchanged (stable support).

__global__ __launch_bounds__(1024) void solver_kernel(const float* __restrict__ rets,
                                                      float* __restrict__ out) {
  __shared__ __align__(16) ushort rowcache[kCacheRows][kN];  // 120 KB; first 32 KB = partials
  __shared__ __align__(16) float yv_s[kN];
  __shared__ __align__(16) float zred_s[kN];
  __shared__ short yi_s[kN];
  __shared__ short cachedrow_s[kCacheRows];
  __shared__ float red_s[8];
  __shared__ int nact_s;
  __shared__ int done_s;

  const int t = threadIdx.x;          // 0..1023
  const int lane = t & 63;
  const int w = t >> 6;               // 0..15
  const int b = blockIdx.x;
  const int4* Q16v = (const int4*)(g_Q16 + (size_t)b * kN * kN);
  const uint2* Q8v = (const uint2*)g_Q8 + (size_t)b * (kN * kN / 8);
  float* partial = reinterpret_cast<float*>(&rowcache[0][0]);  // 16*kN floats (phases 1/A only)

  // ---- power iteration on fp8 Q (30 iters), normalization folded into matvec ----
  if (t < kN) yv_s[t] = 0.044194173824159216f;  // 1/sqrt(512), already unit norm
  if (t == 0) done_s = 0;
  __syncthreads();

  float invn = 1.0f;
  for (int it = 0; it < kPowerIters; ++it) {
    float acc[8] = {0.f, 0.f, 0.f, 0.f, 0.f, 0.f, 0.f, 0.f};
#pragma unroll 8
    for (int k = w; k < kN; k += 16) {
      const uint2 raw = Q8v[(size_t)k * 64 + lane];
      const float yj = yv_s[k];
      acc[0] = fmaf(__builtin_amdgcn_cvt_f32_fp8(raw.x, 0), yj, acc[0]);
      acc[1] = fmaf(__builtin_amdgcn_cvt_f32_fp8(raw.x, 1), yj, acc[1]);
      acc[2] = fmaf(__builtin_amdgcn_cvt_f32_fp8(raw.x, 2), yj, acc[2]);
      acc[3] = fmaf(__builtin_amdgcn_cvt_f32_fp8(raw.x, 3), yj, acc[3]);
      acc[4] = fmaf(__builtin_amdgcn_cvt_f32_fp8(raw.y, 0), yj, acc[4]);
      acc[5] = fmaf(__builtin_amdgcn_cvt_f32_fp8(raw.y, 1), yj, acc[5]);
      acc[6] = fmaf(__builtin_amdgcn_cvt_f32_fp8(raw.y, 2), yj, acc[6]);
      acc[7] = fmaf(__builtin_amdgcn_cvt_f32_fp8(raw.y, 3), yj, acc[7]);
    }
    float4* pp = (float4*)&partial[(w << 9) + (lane << 3)];
    pp[0] = make_float4(acc[0] * invn, acc[1] * invn, acc[2] * invn, acc[3] * invn);
    pp[1] = make_float4(acc[4] * invn, acc[5] * invn, acc[6] * invn, acc[7] * invn);
    __syncthreads();
    if (t < kN) {
      float u = 0.f;
#pragma unroll
      for (int ww = 0; ww < 16; ++ww) u += partial[(ww << 9) + t];
      yv_s[t] = u;                    // unnormalized; next matvec scales by invn
      const float qq = wave_sum64(u * u);
      if (lane == 0) red_s[w] = qq;
    }
    __syncthreads();
    float n2 = 0.f;
#pragma unroll
    for (int i = 0; i < 8; ++i) n2 += red_s[i];
    invn = 1.0f / (sqrtf(n2) + 1e-12f);
  }

  // ---- Rayleigh on fp16 Q: lam = v^T Q v (2nd-order robust to v error) ----
  float eta;
  {
    float acc[8] = {0.f, 0.f, 0.f, 0.f, 0.f, 0.f, 0.f, 0.f};
#pragma unroll 8
    for (int k = w; k < kN; k += 16) {
      const int4 raw = Q16v[(size_t)k * 64 + lane];
      fma8(raw, yv_s[k], acc);
    }
    float4* pp = (float4*)&partial[(w << 9) + (lane << 3)];
    pp[0] = make_float4(acc[0] * invn, acc[1] * invn, acc[2] * invn, acc[3] * invn);
    pp[1] = make_float4(acc[4] * invn, acc[5] * invn, acc[6] * invn, acc[7] * invn);
    __syncthreads();
    if (t < kN) {
      float u = 0.f;
#pragma unroll
      for (int ww = 0; ww < 16; ++ww) u += partial[(ww << 9) + t];
      const float vt = yv_s[t] * invn;
      const float ql = wave_sum64(vt * u);
      if (lane == 0) red_s[w] = ql;
    }
    __syncthreads();
    float lam = 0.f;
#pragma unroll
    for (int i = 0; i < 8; ++i) lam += red_s[i];
    eta = 1.0f / (2.0f * 1.06f * lam + 1e-8f);  // 1.06 safety: fp8 direction noise
  }

  // ---- FISTA init: comp = 8*lane+c on wave0; yi/yv dense ----
  float w8[8], y8[8], r8[8];
  float tf = 1.0f;
  float theta_w = 0.0f;               // Michelot warm-start carry
  unsigned long long m8_prev[8] = {0, 0, 0, 0, 0, 0, 0, 0};
  if (t < kN) { yv_s[t] = 1.0f / 512.0f; yi_s[t] = (short)t; }
  if (t == 0) nact_s = kN;
  if (w == 0) {
    const float4 ra = *(const float4*)(rets + (size_t)b * kN + 8 * lane);
    const float4 rc = *(const float4*)(rets + (size_t)b * kN + 8 * lane + 4);
    r8[0] = ra.x; r8[1] = ra.y; r8[2] = ra.z; r8[3] = ra.w;
    r8[4] = rc.x; r8[5] = rc.y; r8[6] = rc.z; r8[7] = rc.w;
#pragma unroll
    for (int c = 0; c < 8; ++c) { w8[c] = 1.0f / 512.0f; y8[c] = 1.0f / 512.0f; }
  }
  __syncthreads();

  // ---- Phase A: 16-wave iterations while the support is large ----
  int it = 0;
  for (; it < kFistaIters; ++it) {
    const int na = nact_s;
    if (na <= kCacheRows || done_s) break;
    float acc[8] = {0.f, 0.f, 0.f, 0.f, 0.f, 0.f, 0.f, 0.f};
#pragma unroll 8
    for (int k = w; k < na; k += 16) {
      const int row = yi_s[k];
      fma8(Q16v[(size_t)row * 64 + lane], yv_s[k], acc);
    }
    float4* pp = (float4*)&partial[(w << 9) + (lane << 3)];
    pp[0] = make_float4(acc[0], acc[1], acc[2], acc[3]);
    pp[1] = make_float4(acc[4], acc[5], acc[6], acc[7]);
    __syncthreads();
    if (t < kN) {
      float u = 0.f;
#pragma unroll
      for (int ww = 0; ww < 16; ++ww) u += partial[(ww << 9) + t];
      zred_s[t] = u;
    }
    __syncthreads();
    if (w == 0) {
      float z8[8];
      const float4 za = *(const float4*)&zred_s[8 * lane];
      const float4 zb = *(const float4*)&zred_s[8 * lane + 4];
      z8[0] = y8[0] - eta * (2.0f * za.x - r8[0]);
      z8[1] = y8[1] - eta * (2.0f * za.y - r8[1]);
      z8[2] = y8[2] - eta * (2.0f * za.z - r8[2]);
      z8[3] = y8[3] - eta * (2.0f * za.w - r8[3]);
      z8[4] = y8[4] - eta * (2.0f * zb.x - r8[4]);
      z8[5] = y8[5] - eta * (2.0f * zb.y - r8[5]);
      z8[6] = y8[6] - eta * (2.0f * zb.z - r8[6]);
      z8[7] = y8[7] - eta * (2.0f * zb.w - r8[7]);
      float dmax;
      const int nb = fista_proj_update(z8, w8, y8, tf, theta_w, yv_s, yi_s, m8_prev, dmax);
      if (lane == 0) {
        nact_s = nb;
        if (dmax < 1e-7f) done_s = 1;
      }
    }
    __syncthreads();
  }

  const bool finished = (done_s != 0) || (it >= kFistaIters);
  if (!finished) {
    // cooperative cache fill: whole active support -> LDS (16 waves)
    const int naf = nact_s;
    for (int k = w; k < naf; k += 16)
      *(int4*)(&rowcache[k][8 * lane]) = Q16v[(size_t)yi_s[k] * 64 + lane];
    if (t < kCacheRows) cachedrow_s[t] = (t < naf) ? yi_s[t] : (short)-1;
    __syncthreads();
  }
  if (w != 0) return;   // waves 1..15 retire; LDS persists for the block

  if (!finished) {
    // ---- Phase B: single wave, zero barriers ----
    int na = nact_s;
    bool cache_match = true;   // cache was just filled from the current list
    for (; it < kFistaIters; ++it) {
      float acc[8] = {0.f, 0.f, 0.f, 0.f, 0.f, 0.f, 0.f, 0.f};
      const int lim = na < kCacheRows ? na : kCacheRows;

      int P = lim;
      if (!cache_match) {
        // find matching cache prefix [0,P) (compaction order is deterministic)
        for (int k0 = 0; k0 < lim; k0 += 64) {
          const int k = k0 + lane;
          const bool mis = (k < lim) && (cachedrow_s[k] != yi_s[k]);
          const unsigned long long mm = __ballot(mis);
          if (mm) { P = k0 + (int)__ffsll(mm) - 1; break; }
        }
      }

#pragma unroll 8
      for (int k = 0; k < P; ++k)
        fma8(*(const int4*)(&rowcache[k][8 * lane]), yv_s[k], acc);
      for (int k = P; k < lim; ++k) {            // global + refill cache slot k
        const int row = yi_s[k];
        const int4 raw = Q16v[(size_t)row * 64 + lane];
        *(int4*)(&rowcache[k][8 * lane]) = raw;
        if (lane == 0) cachedrow_s[k] = (short)row;
        fma8(raw, yv_s[k], acc);
      }
#pragma unroll 4
      for (int k = lim; k < na; ++k) {           // overflow beyond cache capacity
        const int row = yi_s[k];
        fma8(Q16v[(size_t)row * 64 + lane], yv_s[k], acc);
      }

      float z8[8];
#pragma unroll
      for (int c = 0; c < 8; ++c)
        z8[c] = y8[c] - eta * (2.0f * acc[c] - r8[c]);

      float dmax;
      unsigned long long m8[8];
      na = fista_proj_update(z8, w8, y8, tf, theta_w, yv_s, yi_s, m8, dmax);
      bool same = true;
#pragma unroll
      for (int c = 0; c < 8; ++c) { same = same && (m8[c] == m8_prev[c]); m8_prev[c] = m8[c]; }
      cache_match = same;          // unchanged ballots => identical list => cache still hot
      if (dmax < 1e-7f) break;     // numerical fixed point: rest of iters are no-ops
    }
  }

  *(float4*)(out + (size_t)b * kN + 8 * lane)     = make_float4(w8[0], w8[1], w8[2], w8[3]);
  *(float4*)(out + (size_t)b * kN + 8 * lane + 4) = make_float4(w8[4], w8[5], w8[6], w8[7]);
}

extern "C" void kernel_launch(void* const* d_in, const int* in_sizes, int n_in,
                              void* d_out, int out_size, void* d_ws, size_t ws_size,
                              hipStream_t stream) {
  (void)in_sizes; (void)n_in; (void)out_size; (void)d_ws; (void)ws_size;
  const float* rets  = (const float*)d_in[0];
  const float* cov   = (const float*)d_in[1];
  const float* gamma = (const float*)d_in[2];
  float* out = (float*)d_out;

  transpose_kernel<<<dim3(64, kB), 256, 0, stream>>>(cov);
  build_q_kernel<<<dim3(16, kB), 256, 0, stream>>>(gamma);
  solver_kernel<<<kB, 1024, 0, stream>>>(rets, out);
}